// Round 4
// baseline (2639.226 us; speedup 1.0000x reference)
//
#include <hip/hip_runtime.h>
#include <hip/hip_bf16.h>
#include <math.h>

#define V 32000
#define B 32
#define E 64
#define H 256
#define T 128
#define NROW (B*T)     // 4096 rows, row = t*B + b
#define NC 128         // vocab cols per block (logits)
#define NVB (V/NC)     // 250
#define MR 128         // rows per block (logits)

typedef __attribute__((ext_vector_type(8))) short bf16x8;
typedef __attribute__((ext_vector_type(4))) float f32x4;
typedef __attribute__((ext_vector_type(8))) unsigned short u16x8;

// ws layout (float offsets)
#define OFF_XS   0
#define OFF_XW   (OFF_XS + NROW*E)          // 262144  (xwT bf16 8MB; region reused for WoT after recur)
#define OFF_HB   (OFF_XW + NROW*4*H)        // 4456448 (h bf16: NROW*H ushort = 2MB)
#define OFF_PM   (OFF_HB + NROW*H/2)        // 4980736
#define OFF_PS   (OFF_PM + NVB*NROW)        // 6004736
#define OFF_TL   (OFF_PS + NVB*NROW)        // 7028736 (+4096)
#define OFF_UT   (OFF_TL + NROW)            // 7032832 (UT bf16: 1024*256 ushort = 512KB)

static __device__ __forceinline__ unsigned short f2bf(float f) {
    union { float f; unsigned int u; } x; x.f = f;
    unsigned int r = x.u + 0x7fffu + ((x.u >> 16) & 1u);   // RNE
    return (unsigned short)(r >> 16);
}
static __device__ __forceinline__ float bf2f(unsigned short u) {
    union { unsigned int u; float f; } x; x.u = ((unsigned int)u) << 16; return x.f;
}
static __device__ __forceinline__ float sigmoidf_(float x) { return 1.f / (1.f + __expf(-x)); }
static __device__ __forceinline__ float tanhf_(float x)    { return 2.f / (1.f + __expf(-2.f * x)) - 1.f; }

// ---------------- kernel 1: embedding gather (teacher forcing) ----------------
__global__ void lstm_embed(const int* __restrict__ x, const float* __restrict__ emb,
                           const int* __restrict__ start, float* __restrict__ xs,
                           float* __restrict__ out) {
    int idx = blockIdx.x * 256 + threadIdx.x;
    if (idx == 0) out[0] = 0.f;               // zero accumulator each launch (graph-replay safe)
    if (idx >= T * B * E) return;
    int t   = idx / (B * E);
    int rem = idx - t * (B * E);
    int b   = rem >> 6;
    int e   = rem & 63;
    int tok = (t == 0) ? start[0] : x[b * T + (t - 1)];
    xs[idx] = emb[tok * E + e];
}

// --- kernel 2: xwT[t][j][b][g] bf16 = (xs @ W_g + bias_g), block per t --------
__global__ __launch_bounds__(256) void lstm_xw(
        const float* __restrict__ xs, unsigned short* __restrict__ xwT,
        const float* __restrict__ Wi, const float* __restrict__ Wf,
        const float* __restrict__ Wog, const float* __restrict__ Wc,
        const float* __restrict__ bi, const float* __restrict__ bf,
        const float* __restrict__ bog, const float* __restrict__ bc) {
    __shared__ float xsl[32][65];
    const int t = blockIdx.x, tid = threadIdx.x;
    for (int i = tid; i < 32 * 64; i += 256) {
        int b = i >> 6, e = i & 63;
        xsl[b][e] = xs[(size_t)(t * 32 + b) * 64 + e];
    }
    __syncthreads();
    const int b = tid & 31, jg = tid >> 5;
    for (int jj = 0; jj < 32; ++jj) {
        const int j = jg * 32 + jj;
        float a0 = bi[j], a1 = bf[j], a2 = bog[j], a3 = bc[j];
        #pragma unroll 8
        for (int e = 0; e < E; ++e) {
            float xe = xsl[b][e];
            a0 += xe * Wi [e * H + j];
            a1 += xe * Wf [e * H + j];
            a2 += xe * Wog[e * H + j];
            a3 += xe * Wc [e * H + j];
        }
        ushort4 v;
        v.x = f2bf(a0); v.y = f2bf(a1); v.z = f2bf(a2); v.w = f2bf(a3);
        *(ushort4*)(xwT + ((size_t)(t * 256 + j) * 32 + b) * 4) = v;
    }
}

// ------ kernel 3: U_g[256][256] fp32 -> UT[(j*4+g)][k] bf16 (transposed) -------
__global__ __launch_bounds__(256) void lstm_ut(
        const float* __restrict__ Ui, const float* __restrict__ Uf,
        const float* __restrict__ Uog, const float* __restrict__ Uc,
        unsigned short* __restrict__ UT) {
    __shared__ unsigned short tle[64][65];
    const int g = blockIdx.z;
    const float* U = (g == 0) ? Ui : (g == 1) ? Uf : (g == 2) ? Uog : Uc;
    const int j0 = blockIdx.x * 64, k0 = blockIdx.y * 64;
    const int tid = threadIdx.x;
    for (int i = tid; i < 64 * 64; i += 256) {
        int kk = i >> 6, jj = i & 63;
        tle[kk][jj] = f2bf(U[(size_t)(k0 + kk) * H + j0 + jj]);
    }
    __syncthreads();
    for (int c = tid; c < 512; c += 256) {
        int jj = c >> 3, kc = c & 7;
        u16x8 v;
        #pragma unroll
        for (int e = 0; e < 8; ++e) v[e] = tle[kc * 8 + e][jj];
        *(u16x8*)(UT + ((size_t)(j0 + jj) * 4 + g) * H + k0 + kc * 8) = v;
    }
}

// ---- kernel 4: recurrence, SINGLE 512-thread workgroup, no global sync -------
// wave w owns gate-cols [w*128, w*128+128) = 8 col-frags; cf 0,1 resident in
// VGPRs, cf 2..7 streamed from L2 each step. acc[r] r=0..3 is the (i,f,o,cbar)
// quad for j = w*32+cf*4+lg, batch = lr (+16), so the pointwise LSTM math is
// done in-register by the same lane; c-state never leaves VGPRs.
#define LOADA(dst_, cf_) { _Pragma("unroll") \
    for (int kt_ = 0; kt_ < 8; ++kt_) \
        (dst_)[kt_] = *(const bf16x8*)(UT + (size_t)(colbase + (cf_)*16 + lr) * H + kt_*32 + lg*8); }

#define MFMA8(Afr_) { _Pragma("unroll") \
    for (int kt_ = 0; kt_ < 8; ++kt_) { \
        acc0 = __builtin_amdgcn_mfma_f32_16x16x32_bf16((Afr_)[kt_], Bv0[kt_], acc0, 0, 0, 0); \
        acc1 = __builtin_amdgcn_mfma_f32_16x16x32_bf16((Afr_)[kt_], Bv1[kt_], acc1, 0, 0, 0); } }

#define COMBINE(t_, cf_) { \
    const int j_ = w * 32 + (cf_) * 4 + lg; \
    const unsigned short* xp_ = xwT + ((size_t)((t_) * 256 + j_) * 32) * 4; \
    ushort4 xa_ = *(const ushort4*)(xp_ + lr * 4); \
    ushort4 xb_ = *(const ushort4*)(xp_ + 64 + lr * 4); \
    float pi_ = bf2f(xa_.x) + acc0[0], pf_ = bf2f(xa_.y) + acc0[1]; \
    float po_ = bf2f(xa_.z) + acc0[2], pc_ = bf2f(xa_.w) + acc0[3]; \
    float cc_ = sigmoidf_(pf_) * c_reg[cf_][0] + sigmoidf_(pi_) * tanhf_(pc_); \
    c_reg[cf_][0] = cc_; \
    *(unsigned short*)(hsW + lr * 512 + ((2 * j_) ^ ((lr & 7) << 4))) = f2bf(sigmoidf_(po_) * tanhf_(cc_)); \
    pi_ = bf2f(xb_.x) + acc1[0]; pf_ = bf2f(xb_.y) + acc1[1]; \
    po_ = bf2f(xb_.z) + acc1[2]; pc_ = bf2f(xb_.w) + acc1[3]; \
    cc_ = sigmoidf_(pf_) * c_reg[cf_][1] + sigmoidf_(pi_) * tanhf_(pc_); \
    c_reg[cf_][1] = cc_; \
    *(unsigned short*)(hsW + (16 + lr) * 512 + ((2 * j_) ^ ((lr & 7) << 4))) = f2bf(sigmoidf_(po_) * tanhf_(cc_)); \
}

__global__ __launch_bounds__(512, 2) void lstm_recur1(
        const unsigned short* __restrict__ xwT, const unsigned short* __restrict__ UT,
        unsigned short* __restrict__ hb) {
    __shared__ char h_s[2][16384];              // h double buffer, XOR-swizzled
    const int tid  = threadIdx.x;
    const int lane = tid & 63, w = tid >> 6;    // 8 waves
    const int lr = lane & 15, lg = lane >> 4;
    const int colbase = w * 128;

    bf16x8 Ar0[8], Ar1[8];                      // resident A (cf 0,1)
    LOADA(Ar0, 0);
    LOADA(Ar1, 1);
    bf16x8 SA[8], SB[8];                        // streamed A double buffer
    bf16x8 Bv0[8], Bv1[8];                      // h fragments (loaded once/step)
    float c_reg[8][2] = {};

    // ---- t = 0: gates = xw only (h0 = c0 = 0), write h_s[1] ----
    {
        char* hsW = h_s[1];
        f32x4 acc0 = {}, acc1 = {};
        COMBINE(0, 0) COMBINE(0, 1) COMBINE(0, 2) COMBINE(0, 3)
        COMBINE(0, 4) COMBINE(0, 5) COMBINE(0, 6) COMBINE(0, 7)
        __syncthreads();
        const int o = tid * 32;
        #pragma unroll
        for (int hh = 0; hh < 2; ++hh) {
            int oo = o + hh * 16, row = oo >> 9, col = oo & 511;
            uint4 v = *(const uint4*)(h_s[1] + row * 512 + (col ^ ((row & 7) << 4)));
            *(uint4*)((char*)hb + oo) = v;
        }
    }

    for (int t = 1; t < T; ++t) {
        const char* hsR = h_s[t & 1];
        char*       hsW = h_s[(t & 1) ^ 1];
        #pragma unroll
        for (int kt = 0; kt < 8; ++kt) {
            const int cswz = (kt * 64 + lg * 16) ^ ((lr & 7) << 4);
            Bv0[kt] = *(const bf16x8*)(hsR + lr * 512 + cswz);
            Bv1[kt] = *(const bf16x8*)(hsR + (16 + lr) * 512 + cswz);
        }
        LOADA(SA, 2);
        { f32x4 acc0 = {}, acc1 = {}; MFMA8(Ar0); COMBINE(t, 0) }
        { f32x4 acc0 = {}, acc1 = {}; MFMA8(Ar1); COMBINE(t, 1) }
        LOADA(SB, 3);
        { f32x4 acc0 = {}, acc1 = {}; MFMA8(SA); COMBINE(t, 2) }
        LOADA(SA, 4);
        { f32x4 acc0 = {}, acc1 = {}; MFMA8(SB); COMBINE(t, 3) }
        LOADA(SB, 5);
        { f32x4 acc0 = {}, acc1 = {}; MFMA8(SA); COMBINE(t, 4) }
        LOADA(SA, 6);
        { f32x4 acc0 = {}, acc1 = {}; MFMA8(SB); COMBINE(t, 5) }
        LOADA(SB, 7);
        { f32x4 acc0 = {}, acc1 = {}; MFMA8(SA); COMBINE(t, 6) }
        { f32x4 acc0 = {}, acc1 = {}; MFMA8(SB); COMBINE(t, 7) }
        __syncthreads();
        const int o = tid * 32;
        #pragma unroll
        for (int hh = 0; hh < 2; ++hh) {
            int oo = o + hh * 16, row = oo >> 9, col = oo & 511;
            uint4 v = *(const uint4*)(hsW + row * 512 + (col ^ ((row & 7) << 4)));
            *(uint4*)((char*)hb + (size_t)t * 16384 + oo) = v;
        }
    }
}

// -------- kernel 5: Wo [K=256][V] fp32  ->  WoT [V][K=256] bf16 (transpose) ---
__global__ __launch_bounds__(256) void lstm_wot(const float* __restrict__ Wo,
                                                unsigned short* __restrict__ WoT) {
    __shared__ unsigned short tle[64][65];
    const int n0 = blockIdx.x * 64, k0 = blockIdx.y * 64;
    const int tid = threadIdx.x;
    for (int i = tid; i < 64 * 64; i += 256) {
        int kk = i >> 6, nn = i & 63;
        tle[kk][nn] = f2bf(Wo[(size_t)(k0 + kk) * V + n0 + nn]);
    }
    __syncthreads();
    for (int c = tid; c < 512; c += 256) {
        int nn = c >> 3, kc = c & 7;
        u16x8 v;
        #pragma unroll
        for (int e = 0; e < 8; ++e) v[e] = tle[kc * 8 + e][nn];
        *(u16x8*)(WoT + (size_t)(n0 + nn) * H + k0 + kc * 8) = v;
    }
}

// ------ kernel 6: bf16 MFMA logits GEMM + fused per-(row,vchunk) partials -----
__global__ __launch_bounds__(512) void lstm_logits_mfma(
        const unsigned short* __restrict__ hb, const unsigned short* __restrict__ WoT,
        const float* __restrict__ bo, const int* __restrict__ x,
        float* __restrict__ pm, float* __restrict__ ps, float* __restrict__ tl) {
    __shared__ union {
        unsigned short ab[2][MR * H];   // [0]=A tile 64KB, [1]=B tile 64KB
        float lg[MR * 132];             // logits buffer, used after MFMA
    } sm;
    const int tid = threadIdx.x;
    const int vb  = blockIdx.x * NC;
    const int r0  = blockIdx.y * MR;

    const uint4* srcA = (const uint4*)(hb  + (size_t)r0 * H);
    const uint4* srcB = (const uint4*)(WoT + (size_t)vb * H);
    for (int c = tid; c < MR * H / 8; c += 512) {
        int row = c >> 5, c16 = c & 31;
        uint4 va = srcA[c];
        *(uint4*)((char*)sm.ab[0] + row * 512 + ((c16 ^ (row & 7)) << 4)) = va;
        uint4 vbv = srcB[c];
        *(uint4*)((char*)sm.ab[1] + row * 512 + ((c16 ^ (row & 7)) << 4)) = vbv;
    }
    __syncthreads();

    const int lane = tid & 63, wid = tid >> 6;
    const int wr = wid >> 2, wc = wid & 3;
    const int lr = lane & 15, lg = lane >> 4;
    const int swz = lr & 7;
    f32x4 acc[4][2] = {};
    const char* aBase = (const char*)sm.ab[0] + (wr * 64 + lr) * 512;
    const char* bBase = (const char*)sm.ab[1] + (wc * 32 + lr) * 512;
    #pragma unroll
    for (int ks = 0; ks < 8; ++ks) {
        bf16x8 a[4], bfr[2];
        #pragma unroll
        for (int mf = 0; mf < 4; ++mf)
            a[mf] = *(const bf16x8*)(aBase + mf * 16 * 512 + (((ks * 4 + lg) ^ swz) << 4));
        #pragma unroll
        for (int nf = 0; nf < 2; ++nf)
            bfr[nf] = *(const bf16x8*)(bBase + nf * 16 * 512 + (((ks * 4 + lg) ^ swz) << 4));
        #pragma unroll
        for (int mf = 0; mf < 4; ++mf)
            #pragma unroll
            for (int nf = 0; nf < 2; ++nf)
                acc[mf][nf] = __builtin_amdgcn_mfma_f32_16x16x32_bf16(a[mf], bfr[nf], acc[mf][nf], 0, 0, 0);
    }
    __syncthreads();

    float bocol[2];
    #pragma unroll
    for (int nf = 0; nf < 2; ++nf) bocol[nf] = bo[vb + wc * 32 + nf * 16 + lr];
    #pragma unroll
    for (int mf = 0; mf < 4; ++mf)
        #pragma unroll
        for (int nf = 0; nf < 2; ++nf)
            #pragma unroll
            for (int r = 0; r < 4; ++r) {
                int row = wr * 64 + mf * 16 + lg * 4 + r;
                int col = wc * 32 + nf * 16 + lr;
                sm.lg[row * 132 + col] = acc[mf][nf][r] + bocol[nf];
            }
    __syncthreads();

    {
        const int row = tid >> 2, q = tid & 3;
        const float* lp = &sm.lg[row * 132 + q * 32];
        float m = -1e30f;
        #pragma unroll
        for (int i = 0; i < 32; ++i) m = fmaxf(m, lp[i]);
        m = fmaxf(m, __shfl_xor(m, 1));
        m = fmaxf(m, __shfl_xor(m, 2));
        float s = 0.f;
        #pragma unroll
        for (int i = 0; i < 32; ++i) s += expf(lp[i] - m);
        s += __shfl_xor(s, 1);
        s += __shfl_xor(s, 2);
        if (q == 0) {
            const int gr = r0 + row;
            pm[(size_t)blockIdx.x * NROW + gr] = m;
            ps[(size_t)blockIdx.x * NROW + gr] = s;
            const int tt = gr >> 5, bb = gr & 31;
            const int tgt = x[bb * T + tt];
            if (tgt >= vb && tgt < vb + NC)
                tl[gr] = sm.lg[row * 132 + (tgt - vb)];
        }
    }
}

// ---------------- kernel 7: combine partials, reduce NLL ----------------------
__global__ __launch_bounds__(256) void lstm_lse(
        const float* __restrict__ pm, const float* __restrict__ ps,
        const float* __restrict__ tl, float* __restrict__ out) {
    const int row = blockIdx.x * 256 + threadIdx.x;
    float m = -1e30f, s = 0.f;
    for (int c = 0; c < NVB; ++c) {
        float mc = pm[(size_t)c * NROW + row];
        float sc = ps[(size_t)c * NROW + row];
        if (mc > m) { s = s * expf(m - mc) + sc; m = mc; }
        else        { s += sc * expf(mc - m); }
    }
    float nll = (m + logf(s)) - tl[row];
    __shared__ float red[256];
    red[threadIdx.x] = nll;
    __syncthreads();
    for (int off = 128; off > 0; off >>= 1) {
        if (threadIdx.x < off) red[threadIdx.x] += red[threadIdx.x + off];
        __syncthreads();
    }
    if (threadIdx.x == 0) atomicAdd(out, red[0]);
}

extern "C" void kernel_launch(void* const* d_in, const int* in_sizes, int n_in,
                              void* d_out, int out_size, void* d_ws, size_t ws_size,
                              hipStream_t stream) {
    const int*   x     = (const int*)d_in[0];
    const float* emb   = (const float*)d_in[1];
    const float* Wi    = (const float*)d_in[2];
    const float* Ui    = (const float*)d_in[3];
    const float* bi    = (const float*)d_in[4];
    const float* Wf    = (const float*)d_in[5];
    const float* Uf    = (const float*)d_in[6];
    const float* bf    = (const float*)d_in[7];
    const float* Wog   = (const float*)d_in[8];
    const float* Uog   = (const float*)d_in[9];
    const float* bog   = (const float*)d_in[10];
    const float* Wc    = (const float*)d_in[11];
    const float* Uc    = (const float*)d_in[12];
    const float* bc    = (const float*)d_in[13];
    const float* Wo    = (const float*)d_in[14];
    const float* bo    = (const float*)d_in[15];
    const int*   start = (const int*)d_in[16];
    float* ws  = (float*)d_ws;
    float* out = (float*)d_out;

    float*          xs  = ws + OFF_XS;
    unsigned short* xwT = (unsigned short*)(ws + OFF_XW);
    unsigned short* WoT = (unsigned short*)(ws + OFF_XW);   // aliases xwT (dead after recur)
    unsigned short* hbf = (unsigned short*)(ws + OFF_HB);
    float*          pm  = ws + OFF_PM;
    float*          psB = ws + OFF_PS;
    float*          tlB = ws + OFF_TL;
    unsigned short* UT  = (unsigned short*)(ws + OFF_UT);

    lstm_embed <<<(T * B * E + 255) / 256, 256, 0, stream>>>(x, emb, start, xs, out);
    lstm_xw    <<<T, 256, 0, stream>>>(xs, xwT, Wi, Wf, Wog, Wc, bi, bf, bog, bc);
    lstm_ut    <<<dim3(H / 64, H / 64, 4), 256, 0, stream>>>(Ui, Uf, Uog, Uc, UT);
    lstm_recur1<<<1, 512, 0, stream>>>(xwT, UT, hbf);
    lstm_wot   <<<dim3(V / 64, H / 64), 256, 0, stream>>>(Wo, WoT);
    lstm_logits_mfma<<<dim3(NVB, NROW / MR), 512, 0, stream>>>(hbf, WoT, bo, x, pm, psB, tlB);
    lstm_lse   <<<NROW / 256, 256, 0, stream>>>(pm, psB, tlB, out);
}

// Round 5
// 2621.868 us; speedup vs baseline: 1.0066x; 1.0066x over previous
//
#include <hip/hip_runtime.h>
#include <hip/hip_bf16.h>
#include <math.h>

#define V 32000
#define B 32
#define E 64
#define H 256
#define T 128
#define NROW (B*T)     // 4096 rows, row = t*B + b
#define NC 128         // vocab cols per block (logits)
#define NVB (V/NC)     // 250
#define MR 128         // rows per block (logits)
#define ULW 3          // recur waves sourcing A from LDS (96KB U slice)

typedef __attribute__((ext_vector_type(8))) short bf16x8;
typedef __attribute__((ext_vector_type(4))) float f32x4;
typedef __attribute__((ext_vector_type(8))) unsigned short u16x8;

// ws layout (float offsets)
#define OFF_XS   0
#define OFF_XW   (OFF_XS + NROW*E)          // 262144  (xwT bf16 8MB; region reused for WoT after recur)
#define OFF_HB   (OFF_XW + NROW*4*H)        // 4456448 (h bf16: NROW*H ushort = 2MB)
#define OFF_PM   (OFF_HB + NROW*H/2)        // 4980736
#define OFF_PS   (OFF_PM + NVB*NROW)        // 6004736
#define OFF_TL   (OFF_PS + NVB*NROW)        // 7028736 (+4096)
#define OFF_UT   (OFF_TL + NROW)            // 7032832 (UT bf16: 1024*256 ushort = 512KB)

static __device__ __forceinline__ unsigned short f2bf(float f) {
    union { float f; unsigned int u; } x; x.f = f;
    unsigned int r = x.u + 0x7fffu + ((x.u >> 16) & 1u);   // RNE
    return (unsigned short)(r >> 16);
}
static __device__ __forceinline__ float bf2f(unsigned short u) {
    union { unsigned int u; float f; } x; x.u = ((unsigned int)u) << 16; return x.f;
}
static __device__ __forceinline__ float sigmoidf_(float x) { return 1.f / (1.f + __expf(-x)); }
static __device__ __forceinline__ float tanhf_(float x)    { return 2.f / (1.f + __expf(-2.f * x)) - 1.f; }

// ---------------- kernel 1: embedding gather (teacher forcing) ----------------
__global__ void lstm_embed(const int* __restrict__ x, const float* __restrict__ emb,
                           const int* __restrict__ start, float* __restrict__ xs,
                           float* __restrict__ out) {
    int idx = blockIdx.x * 256 + threadIdx.x;
    if (idx == 0) out[0] = 0.f;               // zero accumulator each launch (graph-replay safe)
    if (idx >= T * B * E) return;
    int t   = idx / (B * E);
    int rem = idx - t * (B * E);
    int b   = rem >> 6;
    int e   = rem & 63;
    int tok = (t == 0) ? start[0] : x[b * T + (t - 1)];
    xs[idx] = emb[tok * E + e];
}

// --- kernel 2: xwT[t][j][b][g] bf16 = (xs @ W_g + bias_g), block per t --------
__global__ __launch_bounds__(256) void lstm_xw(
        const float* __restrict__ xs, unsigned short* __restrict__ xwT,
        const float* __restrict__ Wi, const float* __restrict__ Wf,
        const float* __restrict__ Wog, const float* __restrict__ Wc,
        const float* __restrict__ bi, const float* __restrict__ bf,
        const float* __restrict__ bog, const float* __restrict__ bc) {
    __shared__ float xsl[32][65];
    const int t = blockIdx.x, tid = threadIdx.x;
    for (int i = tid; i < 32 * 64; i += 256) {
        int b = i >> 6, e = i & 63;
        xsl[b][e] = xs[(size_t)(t * 32 + b) * 64 + e];
    }
    __syncthreads();
    const int b = tid & 31, jg = tid >> 5;
    for (int jj = 0; jj < 32; ++jj) {
        const int j = jg * 32 + jj;
        float a0 = bi[j], a1 = bf[j], a2 = bog[j], a3 = bc[j];
        #pragma unroll 8
        for (int e = 0; e < E; ++e) {
            float xe = xsl[b][e];
            a0 += xe * Wi [e * H + j];
            a1 += xe * Wf [e * H + j];
            a2 += xe * Wog[e * H + j];
            a3 += xe * Wc [e * H + j];
        }
        ushort4 v;
        v.x = f2bf(a0); v.y = f2bf(a1); v.z = f2bf(a2); v.w = f2bf(a3);
        *(ushort4*)(xwT + ((size_t)(t * 256 + j) * 32 + b) * 4) = v;
    }
}

// ------ kernel 3: U_g[256][256] fp32 -> UT[(j*4+g)][k] bf16 (transposed) -------
__global__ __launch_bounds__(256) void lstm_ut(
        const float* __restrict__ Ui, const float* __restrict__ Uf,
        const float* __restrict__ Uog, const float* __restrict__ Uc,
        unsigned short* __restrict__ UT) {
    __shared__ unsigned short tle[64][65];
    const int g = blockIdx.z;
    const float* U = (g == 0) ? Ui : (g == 1) ? Uf : (g == 2) ? Uog : Uc;
    const int j0 = blockIdx.x * 64, k0 = blockIdx.y * 64;
    const int tid = threadIdx.x;
    for (int i = tid; i < 64 * 64; i += 256) {
        int kk = i >> 6, jj = i & 63;
        tle[kk][jj] = f2bf(U[(size_t)(k0 + kk) * H + j0 + jj]);
    }
    __syncthreads();
    for (int c = tid; c < 512; c += 256) {
        int jj = c >> 3, kc = c & 7;
        u16x8 v;
        #pragma unroll
        for (int e = 0; e < 8; ++e) v[e] = tle[kc * 8 + e][jj];
        *(u16x8*)(UT + ((size_t)(j0 + jj) * 4 + g) * H + k0 + kc * 8) = v;
    }
}

// ---- kernel 4: recurrence, SINGLE 1024-thread workgroup -----------------------
// 16 waves, wave w owns gate-cols [w*64, w*64+64) (j in [w*16, w*16+16)).
// U^T streamed from L2 each step (waves 0..ULW-1 read a 96KB LDS-resident slice
// instead). acc[cf][bt][r] r=0..3 = (i,f,o,cbar) for j=w*16+cf*4+lg, batch=
// bt*16+lr -> pointwise LSTM in-register, c never leaves VGPRs.
// Register budget/wave: acc 32 + Af 16 + B 8 + xw 16 + c 8 + misc ~20 = ~100.
__global__ __launch_bounds__(1024, 4) void lstm_recur1(
        const unsigned short* __restrict__ xwT, const unsigned short* __restrict__ UT,
        unsigned short* __restrict__ hb) {
    __shared__ char h_s[2][16384];              // h double buffer, XOR-swizzled
    __shared__ char u_s[ULW * 32768];           // 96KB U slice (frag layout)
    const int tid  = threadIdx.x;
    const int lane = tid & 63, w = tid >> 6;    // 16 waves
    const int lr = lane & 15, lg = lane >> 4;
    const int colbase = w * 64;
    const int swz = (lr & 7) << 4;

    // ---- stage U-slice for waves 0..ULW-1 into LDS (frag-layout, linear) ----
    for (int c = tid; c < ULW * 2048; c += 1024) {   // 16B chunks
        int s = c >> 6, l = c & 63;
        int ws_ = s >> 5, r = s & 31;
        int kh = r >> 4, kt = (r >> 2) & 3, cf = r & 3;
        int col = ws_ * 64 + cf * 16 + (l & 15);
        int k   = kh * 128 + kt * 32 + (l >> 4) * 8;
        *(uint4*)(u_s + (size_t)s * 1024 + l * 16) = *(const uint4*)(UT + (size_t)col * H + k);
    }

    float c_reg[4][2] = {};

    // ---- t = 0: gates = xw only (h0 = c0 = 0) ----
    {
        char* hsW = h_s[1];
        #pragma unroll
        for (int cf = 0; cf < 4; ++cf) {
            const int j_ = w * 16 + cf * 4 + lg;
            const unsigned short* xp = xwT + ((size_t)j_ * 32 + lr) * 4;
            #pragma unroll
            for (int bt = 0; bt < 2; ++bt) {
                ushort4 xa = *(const ushort4*)(xp + bt * 64);
                float pi = bf2f(xa.x), pf = bf2f(xa.y), po = bf2f(xa.z), pc = bf2f(xa.w);
                float cc = sigmoidf_(pi) * tanhf_(pc);     // f*c0 = 0
                c_reg[cf][bt] = cc;
                int bat = bt * 16 + lr;
                *(unsigned short*)(hsW + bat * 512 + ((2 * j_) ^ ((bat & 7) << 4)))
                    = f2bf(sigmoidf_(po) * tanhf_(cc));
            }
        }
        __syncthreads();   // covers u_s staging + h_s[1] writes
        int oo = tid * 16, row = oo >> 9, colb = oo & 511;
        *(uint4*)((char*)hb + oo) =
            *(const uint4*)(h_s[1] + row * 512 + (colb ^ ((row & 7) << 4)));
    }

    // A-frag loads: LDS path for w<ULW, global path otherwise (wave-uniform).
    #define AF_LDS(kh_, kt_, cf_) \
        *(const bf16x8*)(u_s + ((size_t)(w * 32 + (kh_) * 16 + (kt_) * 4 + (cf_)) * 1024) + lane * 16)
    #define AF_GBL(kh_, kt_, cf_) \
        *(const bf16x8*)(UT + (size_t)(colbase + (cf_) * 16 + lr) * H + (kh_) * 128 + (kt_) * 32 + lg * 8)

    #define KLOOP(AF_) { _Pragma("unroll") \
        for (int kh = 0; kh < 2; ++kh) { _Pragma("unroll") \
            for (int kt = 0; kt < 4; ++kt) { \
                const int cswz = kh * 256 + kt * 64 + lg * 16; \
                bf16x8 B0 = *(const bf16x8*)(hsR + lr * 512 + (cswz ^ swz)); \
                bf16x8 B1 = *(const bf16x8*)(hsR + (16 + lr) * 512 + (cswz ^ swz)); \
                bf16x8 Af0 = AF_(kh, kt, 0), Af1 = AF_(kh, kt, 1); \
                bf16x8 Af2 = AF_(kh, kt, 2), Af3 = AF_(kh, kt, 3); \
                acc[0][0] = __builtin_amdgcn_mfma_f32_16x16x32_bf16(Af0, B0, acc[0][0], 0, 0, 0); \
                acc[0][1] = __builtin_amdgcn_mfma_f32_16x16x32_bf16(Af0, B1, acc[0][1], 0, 0, 0); \
                acc[1][0] = __builtin_amdgcn_mfma_f32_16x16x32_bf16(Af1, B0, acc[1][0], 0, 0, 0); \
                acc[1][1] = __builtin_amdgcn_mfma_f32_16x16x32_bf16(Af1, B1, acc[1][1], 0, 0, 0); \
                acc[2][0] = __builtin_amdgcn_mfma_f32_16x16x32_bf16(Af2, B0, acc[2][0], 0, 0, 0); \
                acc[2][1] = __builtin_amdgcn_mfma_f32_16x16x32_bf16(Af2, B1, acc[2][1], 0, 0, 0); \
                acc[3][0] = __builtin_amdgcn_mfma_f32_16x16x32_bf16(Af3, B0, acc[3][0], 0, 0, 0); \
                acc[3][1] = __builtin_amdgcn_mfma_f32_16x16x32_bf16(Af3, B1, acc[3][1], 0, 0, 0); \
            } } }

    #pragma unroll 1
    for (int t = 1; t < T; ++t) {
        const char* hsR = h_s[t & 1];
        char*       hsW = h_s[(t & 1) ^ 1];

        // xw loads issued early, consumed in combine (~whole step of cover)
        ushort4 xw4[4][2];
        #pragma unroll
        for (int cf = 0; cf < 4; ++cf) {
            const int j_ = w * 16 + cf * 4 + lg;
            const unsigned short* xp = xwT + ((size_t)(t * 256 + j_) * 32 + lr) * 4;
            xw4[cf][0] = *(const ushort4*)xp;
            xw4[cf][1] = *(const ushort4*)(xp + 64);
        }

        f32x4 acc[4][2] = {};
        if (w < ULW) KLOOP(AF_LDS) else KLOOP(AF_GBL)

        #pragma unroll
        for (int cf = 0; cf < 4; ++cf) {
            const int j_ = w * 16 + cf * 4 + lg;
            #pragma unroll
            for (int bt = 0; bt < 2; ++bt) {
                float pi = bf2f(xw4[cf][bt].x) + acc[cf][bt][0];
                float pf = bf2f(xw4[cf][bt].y) + acc[cf][bt][1];
                float po = bf2f(xw4[cf][bt].z) + acc[cf][bt][2];
                float pc = bf2f(xw4[cf][bt].w) + acc[cf][bt][3];
                float cc = sigmoidf_(pf) * c_reg[cf][bt] + sigmoidf_(pi) * tanhf_(pc);
                c_reg[cf][bt] = cc;
                int bat = bt * 16 + lr;
                *(unsigned short*)(hsW + bat * 512 + ((2 * j_) ^ ((bat & 7) << 4)))
                    = f2bf(sigmoidf_(po) * tanhf_(cc));
            }
        }
        __syncthreads();
        int oo = tid * 16, row = oo >> 9, colb = oo & 511;
        *(uint4*)((char*)hb + (size_t)t * 16384 + oo) =
            *(const uint4*)(hsW + row * 512 + (colb ^ ((row & 7) << 4)));
    }
}

// -------- kernel 5: Wo [K=256][V] fp32  ->  WoT [V][K=256] bf16 (transpose) ---
__global__ __launch_bounds__(256) void lstm_wot(const float* __restrict__ Wo,
                                                unsigned short* __restrict__ WoT) {
    __shared__ unsigned short tle[64][65];
    const int n0 = blockIdx.x * 64, k0 = blockIdx.y * 64;
    const int tid = threadIdx.x;
    for (int i = tid; i < 64 * 64; i += 256) {
        int kk = i >> 6, nn = i & 63;
        tle[kk][nn] = f2bf(Wo[(size_t)(k0 + kk) * V + n0 + nn]);
    }
    __syncthreads();
    for (int c = tid; c < 512; c += 256) {
        int nn = c >> 3, kc = c & 7;
        u16x8 v;
        #pragma unroll
        for (int e = 0; e < 8; ++e) v[e] = tle[kc * 8 + e][nn];
        *(u16x8*)(WoT + (size_t)(n0 + nn) * H + k0 + kc * 8) = v;
    }
}

// ------ kernel 6: bf16 MFMA logits GEMM + fused per-(row,vchunk) partials -----
__global__ __launch_bounds__(512) void lstm_logits_mfma(
        const unsigned short* __restrict__ hb, const unsigned short* __restrict__ WoT,
        const float* __restrict__ bo, const int* __restrict__ x,
        float* __restrict__ pm, float* __restrict__ ps, float* __restrict__ tl) {
    __shared__ union {
        unsigned short ab[2][MR * H];   // [0]=A tile 64KB, [1]=B tile 64KB
        float lg[MR * 132];             // logits buffer, used after MFMA
    } sm;
    const int tid = threadIdx.x;
    const int vb  = blockIdx.x * NC;
    const int r0  = blockIdx.y * MR;

    const uint4* srcA = (const uint4*)(hb  + (size_t)r0 * H);
    const uint4* srcB = (const uint4*)(WoT + (size_t)vb * H);
    for (int c = tid; c < MR * H / 8; c += 512) {
        int row = c >> 5, c16 = c & 31;
        uint4 va = srcA[c];
        *(uint4*)((char*)sm.ab[0] + row * 512 + ((c16 ^ (row & 7)) << 4)) = va;
        uint4 vbv = srcB[c];
        *(uint4*)((char*)sm.ab[1] + row * 512 + ((c16 ^ (row & 7)) << 4)) = vbv;
    }
    __syncthreads();

    const int lane = tid & 63, wid = tid >> 6;
    const int wr = wid >> 2, wc = wid & 3;
    const int lr = lane & 15, lg = lane >> 4;
    const int swz = lr & 7;
    f32x4 acc[4][2] = {};
    const char* aBase = (const char*)sm.ab[0] + (wr * 64 + lr) * 512;
    const char* bBase = (const char*)sm.ab[1] + (wc * 32 + lr) * 512;
    #pragma unroll
    for (int ks = 0; ks < 8; ++ks) {
        bf16x8 a[4], bfr[2];
        #pragma unroll
        for (int mf = 0; mf < 4; ++mf)
            a[mf] = *(const bf16x8*)(aBase + mf * 16 * 512 + (((ks * 4 + lg) ^ swz) << 4));
        #pragma unroll
        for (int nf = 0; nf < 2; ++nf)
            bfr[nf] = *(const bf16x8*)(bBase + nf * 16 * 512 + (((ks * 4 + lg) ^ swz) << 4));
        #pragma unroll
        for (int mf = 0; mf < 4; ++mf)
            #pragma unroll
            for (int nf = 0; nf < 2; ++nf)
                acc[mf][nf] = __builtin_amdgcn_mfma_f32_16x16x32_bf16(a[mf], bfr[nf], acc[mf][nf], 0, 0, 0);
    }
    __syncthreads();

    float bocol[2];
    #pragma unroll
    for (int nf = 0; nf < 2; ++nf) bocol[nf] = bo[vb + wc * 32 + nf * 16 + lr];
    #pragma unroll
    for (int mf = 0; mf < 4; ++mf)
        #pragma unroll
        for (int nf = 0; nf < 2; ++nf)
            #pragma unroll
            for (int r = 0; r < 4; ++r) {
                int row = wr * 64 + mf * 16 + lg * 4 + r;
                int col = wc * 32 + nf * 16 + lr;
                sm.lg[row * 132 + col] = acc[mf][nf][r] + bocol[nf];
            }
    __syncthreads();

    {
        const int row = tid >> 2, q = tid & 3;
        const float* lp = &sm.lg[row * 132 + q * 32];
        float m = -1e30f;
        #pragma unroll
        for (int i = 0; i < 32; ++i) m = fmaxf(m, lp[i]);
        m = fmaxf(m, __shfl_xor(m, 1));
        m = fmaxf(m, __shfl_xor(m, 2));
        float s = 0.f;
        #pragma unroll
        for (int i = 0; i < 32; ++i) s += expf(lp[i] - m);
        s += __shfl_xor(s, 1);
        s += __shfl_xor(s, 2);
        if (q == 0) {
            const int gr = r0 + row;
            pm[(size_t)blockIdx.x * NROW + gr] = m;
            ps[(size_t)blockIdx.x * NROW + gr] = s;
            const int tt = gr >> 5, bb = gr & 31;
            const int tgt = x[bb * T + tt];
            if (tgt >= vb && tgt < vb + NC)
                tl[gr] = sm.lg[row * 132 + (tgt - vb)];
        }
    }
}

// ---------------- kernel 7: combine partials, reduce NLL ----------------------
__global__ __launch_bounds__(256) void lstm_lse(
        const float* __restrict__ pm, const float* __restrict__ ps,
        const float* __restrict__ tl, float* __restrict__ out) {
    const int row = blockIdx.x * 256 + threadIdx.x;
    float m = -1e30f, s = 0.f;
    for (int c = 0; c < NVB; ++c) {
        float mc = pm[(size_t)c * NROW + row];
        float sc = ps[(size_t)c * NROW + row];
        if (mc > m) { s = s * expf(m - mc) + sc; m = mc; }
        else        { s += sc * expf(mc - m); }
    }
    float nll = (m + logf(s)) - tl[row];
    __shared__ float red[256];
    red[threadIdx.x] = nll;
    __syncthreads();
    for (int off = 128; off > 0; off >>= 1) {
        if (threadIdx.x < off) red[threadIdx.x] += red[threadIdx.x + off];
        __syncthreads();
    }
    if (threadIdx.x == 0) atomicAdd(out, red[0]);
}

extern "C" void kernel_launch(void* const* d_in, const int* in_sizes, int n_in,
                              void* d_out, int out_size, void* d_ws, size_t ws_size,
                              hipStream_t stream) {
    const int*   x     = (const int*)d_in[0];
    const float* emb   = (const float*)d_in[1];
    const float* Wi    = (const float*)d_in[2];
    const float* Ui    = (const float*)d_in[3];
    const float* bi    = (const float*)d_in[4];
    const float* Wf    = (const float*)d_in[5];
    const float* Uf    = (const float*)d_in[6];
    const float* bf    = (const float*)d_in[7];
    const float* Wog   = (const float*)d_in[8];
    const float* Uog   = (const float*)d_in[9];
    const float* bog   = (const float*)d_in[10];
    const float* Wc    = (const float*)d_in[11];
    const float* Uc    = (const float*)d_in[12];
    const float* bc    = (const float*)d_in[13];
    const float* Wo    = (const float*)d_in[14];
    const float* bo    = (const float*)d_in[15];
    const int*   start = (const int*)d_in[16];
    float* ws  = (float*)d_ws;
    float* out = (float*)d_out;

    float*          xs  = ws + OFF_XS;
    unsigned short* xwT = (unsigned short*)(ws + OFF_XW);
    unsigned short* WoT = (unsigned short*)(ws + OFF_XW);   // aliases xwT (dead after recur)
    unsigned short* hbf = (unsigned short*)(ws + OFF_HB);
    float*          pm  = ws + OFF_PM;
    float*          psB = ws + OFF_PS;
    float*          tlB = ws + OFF_TL;
    unsigned short* UT  = (unsigned short*)(ws + OFF_UT);

    lstm_embed <<<(T * B * E + 255) / 256, 256, 0, stream>>>(x, emb, start, xs, out);
    lstm_xw    <<<T, 256, 0, stream>>>(xs, xwT, Wi, Wf, Wog, Wc, bi, bf, bog, bc);
    lstm_ut    <<<dim3(H / 64, H / 64, 4), 256, 0, stream>>>(Ui, Uf, Uog, Uc, UT);
    lstm_recur1<<<1, 1024, 0, stream>>>(xwT, UT, hbf);
    lstm_wot   <<<dim3(V / 64, H / 64), 256, 0, stream>>>(Wo, WoT);
    lstm_logits_mfma<<<dim3(NVB, NROW / MR), 512, 0, stream>>>(hbf, WoT, bo, x, pm, psB, tlB);
    lstm_lse   <<<NROW / 256, 256, 0, stream>>>(pm, psB, tlB, out);
}

// Round 6
// 1580.974 us; speedup vs baseline: 1.6694x; 1.6584x over previous
//
#include <hip/hip_runtime.h>
#include <hip/hip_bf16.h>
#include <math.h>

#define V 32000
#define B 32
#define E 64
#define H 256
#define T 128
#define NROW (B*T)     // 4096 rows, row = t*B + b
#define NC 128         // vocab cols per block (logits)
#define NVB (V/NC)     // 250
#define MR 128         // rows per block (logits)
#define RB 8           // recurrence blocks (one U-slice each, LDS-resident)

typedef __attribute__((ext_vector_type(8))) short bf16x8;
typedef __attribute__((ext_vector_type(4))) float f32x4;
typedef __attribute__((ext_vector_type(8))) unsigned short u16x8;

// ws layout (float offsets)
#define OFF_XS   0
#define OFF_XW   (OFF_XS + NROW*E)          // 262144  (xwT bf16 8MB; reused for WoT after recur)
#define OFF_HB   (OFF_XW + NROW*4*H)        // 4456448 (h bf16: NROW*H ushort = 2MB)
#define OFF_PM   (OFF_HB + NROW*H/2)        // 4980736
#define OFF_PS   (OFF_PM + NVB*NROW)        // 6004736
#define OFF_TL   (OFF_PS + NVB*NROW)        // 7028736 (+4096)
#define OFF_UT   (OFF_TL + NROW)            // 7032832 (UT bf16: 1024*256 ushort = 512KB)
#define OFF_HC   (OFF_UT + 4*H*H/2)         // 7163904 (h ping-pong: 2*32*256 ushort = 32KB)
#define OFF_BAR  (OFF_HC + 2*B*H/2)         // 7168000 (+16)  total ~28.7 MB

static __device__ __forceinline__ unsigned short f2bf(float f) {
    union { float f; unsigned int u; } x; x.f = f;
    unsigned int r = x.u + 0x7fffu + ((x.u >> 16) & 1u);   // RNE
    return (unsigned short)(r >> 16);
}
static __device__ __forceinline__ float bf2f(unsigned short u) {
    union { unsigned int u; float f; } x; x.u = ((unsigned int)u) << 16; return x.f;
}
static __device__ __forceinline__ float sigmoidf_(float x) { return 1.f / (1.f + __expf(-x)); }
static __device__ __forceinline__ float tanhf_(float x)    { return 2.f / (1.f + __expf(-2.f * x)) - 1.f; }

// ---------------- kernel 1: embedding gather (teacher forcing) ----------------
__global__ void lstm_embed(const int* __restrict__ x, const float* __restrict__ emb,
                           const int* __restrict__ start, float* __restrict__ xs,
                           float* __restrict__ out, unsigned int* __restrict__ bar) {
    int idx = blockIdx.x * 256 + threadIdx.x;
    if (idx == 0) {
        out[0] = 0.f;   // zero accumulator each launch (graph-replay safe)
        __hip_atomic_store(bar, 0u, __ATOMIC_RELAXED, __HIP_MEMORY_SCOPE_AGENT);
    }
    if (idx >= T * B * E) return;
    int t   = idx / (B * E);
    int rem = idx - t * (B * E);
    int b   = rem >> 6;
    int e   = rem & 63;
    int tok = (t == 0) ? start[0] : x[b * T + (t - 1)];
    xs[idx] = emb[tok * E + e];
}

// --- kernel 2: xwT[t][j][b][g] bf16 = (xs @ W_g + bias_g), block per t --------
__global__ __launch_bounds__(256) void lstm_xw(
        const float* __restrict__ xs, unsigned short* __restrict__ xwT,
        const float* __restrict__ Wi, const float* __restrict__ Wf,
        const float* __restrict__ Wog, const float* __restrict__ Wc,
        const float* __restrict__ bi, const float* __restrict__ bf,
        const float* __restrict__ bog, const float* __restrict__ bc) {
    __shared__ float xsl[32][65];
    const int t = blockIdx.x, tid = threadIdx.x;
    for (int i = tid; i < 32 * 64; i += 256) {
        int b = i >> 6, e = i & 63;
        xsl[b][e] = xs[(size_t)(t * 32 + b) * 64 + e];
    }
    __syncthreads();
    const int b = tid & 31, jg = tid >> 5;
    for (int jj = 0; jj < 32; ++jj) {
        const int j = jg * 32 + jj;
        float a0 = bi[j], a1 = bf[j], a2 = bog[j], a3 = bc[j];
        #pragma unroll 8
        for (int e = 0; e < E; ++e) {
            float xe = xsl[b][e];
            a0 += xe * Wi [e * H + j];
            a1 += xe * Wf [e * H + j];
            a2 += xe * Wog[e * H + j];
            a3 += xe * Wc [e * H + j];
        }
        ushort4 v;
        v.x = f2bf(a0); v.y = f2bf(a1); v.z = f2bf(a2); v.w = f2bf(a3);
        *(ushort4*)(xwT + ((size_t)(t * 256 + j) * 32 + b) * 4) = v;
    }
}

// ------ kernel 3: U_g[256][256] fp32 -> UT[(j*4+g)][k] bf16 (transposed) -------
__global__ __launch_bounds__(256) void lstm_ut(
        const float* __restrict__ Ui, const float* __restrict__ Uf,
        const float* __restrict__ Uog, const float* __restrict__ Uc,
        unsigned short* __restrict__ UT) {
    __shared__ unsigned short tle[64][65];
    const int g = blockIdx.z;
    const float* U = (g == 0) ? Ui : (g == 1) ? Uf : (g == 2) ? Uog : Uc;
    const int j0 = blockIdx.x * 64, k0 = blockIdx.y * 64;
    const int tid = threadIdx.x;
    for (int i = tid; i < 64 * 64; i += 256) {
        int kk = i >> 6, jj = i & 63;
        tle[kk][jj] = f2bf(U[(size_t)(k0 + kk) * H + j0 + jj]);
    }
    __syncthreads();
    for (int c = tid; c < 512; c += 256) {
        int jj = c >> 3, kc = c & 7;
        u16x8 v;
        #pragma unroll
        for (int e = 0; e < 8; ++e) v[e] = tle[kc * 8 + e][jj];
        *(u16x8*)(UT + ((size_t)(j0 + jj) * 4 + g) * H + k0 + kc * 8) = v;
    }
}

// ---- kernel 4: recurrence, 8 blocks, U-slice in LDS, MALL-atomic h exchange --
// Block blk owns j in [blk*32, blk*32+32) (gate-cols [blk*128, +128)).
// Wave w (0..7) owns gate-cols [blk*128+w*16, +16): 8 kt x 2 bt MFMAs into
// acc[bt]; lane (lr,lg) gets acc[bt][r] = gate r (i,f,o,cbar) of j=blk*32+w*4+lg
// for batch bt*16+lr -> pointwise LSTM in-register, c in 2 VGPRs.
// h exchanged via relaxed agent-scope atomics (write-through to MALL; readers
// bypass stale per-XCD L2). Order: stores -> vmcnt(0) -> barrier -> flag add.
__global__ __launch_bounds__(512, 2) void lstm_recur8(
        const unsigned short* __restrict__ xwT, const unsigned short* __restrict__ UT,
        unsigned short* __restrict__ hcm, unsigned short* __restrict__ hb,
        unsigned int* __restrict__ bar) {
    __shared__ char u_s[65536];                 // U-slice, frag layout [w][kt][lane]*16B
    __shared__ unsigned short h_pack[32][32];   // [batch][j_local]
    const int tid = threadIdx.x, blk = blockIdx.x;
    const int lane = tid & 63, w = tid >> 6;
    const int lr = lane & 15, lg = lane >> 4;

    for (int c = tid; c < 4096; c += 512) {     // stage 64KB U-slice once
        int fw = c >> 9, kt = (c >> 6) & 7, l = c & 63;
        int col = blk * 128 + fw * 16 + (l & 15);
        int k   = kt * 32 + (l >> 4) * 8;
        *(uint4*)(u_s + (size_t)c * 16) = *(const uint4*)(UT + (size_t)col * H + k);
    }
    __syncthreads();

    const int j = blk * 32 + w * 4 + lg;
    float c0 = 0.f, c1 = 0.f;

    for (int t = 0; t < T; ++t) {
        const unsigned short* xp = xwT + ((size_t)(t * 256 + j) * 32) * 4;
        ushort4 xw0 = *(const ushort4*)(xp + lr * 4);
        ushort4 xw1 = *(const ushort4*)(xp + (16 + lr) * 4);

        f32x4 acc0 = {}, acc1 = {};
        if (t > 0) {
            const unsigned long long* hsrc =
                (const unsigned long long*)(hcm + ((t - 1) & 1) * (B * H));
            unsigned long long bq[2][8][2];
            #pragma unroll
            for (int kt = 0; kt < 8; ++kt)
                #pragma unroll
                for (int bt = 0; bt < 2; ++bt) {
                    size_t base = ((size_t)(bt * 16 + lr) * H + kt * 32 + lg * 8) >> 2;
                    bq[bt][kt][0] = __hip_atomic_load(hsrc + base,     __ATOMIC_RELAXED, __HIP_MEMORY_SCOPE_AGENT);
                    bq[bt][kt][1] = __hip_atomic_load(hsrc + base + 1, __ATOMIC_RELAXED, __HIP_MEMORY_SCOPE_AGENT);
                }
            #pragma unroll
            for (int kt = 0; kt < 8; ++kt) {
                bf16x8 Af = *(const bf16x8*)(u_s + ((size_t)(w * 8 + kt) * 64 + lane) * 16);
                union { unsigned long long q[2]; bf16x8 v; } b0, b1;
                b0.q[0] = bq[0][kt][0]; b0.q[1] = bq[0][kt][1];
                b1.q[0] = bq[1][kt][0]; b1.q[1] = bq[1][kt][1];
                acc0 = __builtin_amdgcn_mfma_f32_16x16x32_bf16(Af, b0.v, acc0, 0, 0, 0);
                acc1 = __builtin_amdgcn_mfma_f32_16x16x32_bf16(Af, b1.v, acc1, 0, 0, 0);
            }
        }
        // pointwise LSTM (gate quad is in-lane: acc[r] = i,f,o,cbar)
        {
            float pi = bf2f(xw0.x) + acc0[0], pf = bf2f(xw0.y) + acc0[1];
            float po = bf2f(xw0.z) + acc0[2], pc = bf2f(xw0.w) + acc0[3];
            c0 = sigmoidf_(pf) * c0 + sigmoidf_(pi) * tanhf_(pc);
            h_pack[lr][w * 4 + lg] = f2bf(sigmoidf_(po) * tanhf_(c0));
            pi = bf2f(xw1.x) + acc1[0]; pf = bf2f(xw1.y) + acc1[1];
            po = bf2f(xw1.z) + acc1[2]; pc = bf2f(xw1.w) + acc1[3];
            c1 = sigmoidf_(pf) * c1 + sigmoidf_(pi) * tanhf_(pc);
            h_pack[16 + lr][w * 4 + lg] = f2bf(sigmoidf_(po) * tanhf_(c1));
        }
        __syncthreads();
        // pack-store: thread -> (batch b, dword dw) of this block's 2KB slice
        {
            const int b = tid >> 4, dw = tid & 15;
            unsigned int dwv = *(const unsigned int*)&h_pack[b][dw * 2];
            *(unsigned int*)(hb + (size_t)(t * B + b) * H + blk * 32 + dw * 2) = dwv;
            if (t < T - 1) {
                unsigned int* dst = (unsigned int*)(hcm + (t & 1) * (B * H)) + b * (H / 2) + blk * 16 + dw;
                __hip_atomic_store(dst, dwv, __ATOMIC_RELAXED, __HIP_MEMORY_SCOPE_AGENT);
            }
        }
        if (t < T - 1) {
            asm volatile("s_waitcnt vmcnt(0)" ::: "memory");  // h stores ack'd at MALL (per-wave)
            __syncthreads();                                  // all waves' stores done
            if (tid == 0) {
                __hip_atomic_fetch_add(bar, 1u, __ATOMIC_RELAXED, __HIP_MEMORY_SCOPE_AGENT);
                const unsigned int tgt = (unsigned int)(RB * (t + 1));
                while (__hip_atomic_load(bar, __ATOMIC_RELAXED, __HIP_MEMORY_SCOPE_AGENT) < tgt)
                    __builtin_amdgcn_s_sleep(1);
            }
            __syncthreads();
        }
    }
}

// -------- kernel 5: Wo [K=256][V] fp32  ->  WoT [V][K=256] bf16 (transpose) ---
__global__ __launch_bounds__(256) void lstm_wot(const float* __restrict__ Wo,
                                                unsigned short* __restrict__ WoT) {
    __shared__ unsigned short tle[64][65];
    const int n0 = blockIdx.x * 64, k0 = blockIdx.y * 64;
    const int tid = threadIdx.x;
    for (int i = tid; i < 64 * 64; i += 256) {
        int kk = i >> 6, nn = i & 63;
        tle[kk][nn] = f2bf(Wo[(size_t)(k0 + kk) * V + n0 + nn]);
    }
    __syncthreads();
    for (int c = tid; c < 512; c += 256) {
        int nn = c >> 3, kc = c & 7;
        u16x8 v;
        #pragma unroll
        for (int e = 0; e < 8; ++e) v[e] = tle[kc * 8 + e][nn];
        *(u16x8*)(WoT + (size_t)(n0 + nn) * H + k0 + kc * 8) = v;
    }
}

// ------ kernel 6: bf16 MFMA logits GEMM + fused per-(row,vchunk) partials -----
__global__ __launch_bounds__(512) void lstm_logits_mfma(
        const unsigned short* __restrict__ hb, const unsigned short* __restrict__ WoT,
        const float* __restrict__ bo, const int* __restrict__ x,
        float* __restrict__ pm, float* __restrict__ ps, float* __restrict__ tl) {
    __shared__ union {
        unsigned short ab[2][MR * H];   // [0]=A tile 64KB, [1]=B tile 64KB
        float lg[MR * 132];             // logits buffer, used after MFMA
    } sm;
    const int tid = threadIdx.x;
    const int vb  = blockIdx.x * NC;
    const int r0  = blockIdx.y * MR;

    const uint4* srcA = (const uint4*)(hb  + (size_t)r0 * H);
    const uint4* srcB = (const uint4*)(WoT + (size_t)vb * H);
    for (int c = tid; c < MR * H / 8; c += 512) {
        int row = c >> 5, c16 = c & 31;
        uint4 va = srcA[c];
        *(uint4*)((char*)sm.ab[0] + row * 512 + ((c16 ^ (row & 7)) << 4)) = va;
        uint4 vbv = srcB[c];
        *(uint4*)((char*)sm.ab[1] + row * 512 + ((c16 ^ (row & 7)) << 4)) = vbv;
    }
    __syncthreads();

    const int lane = tid & 63, wid = tid >> 6;
    const int wr = wid >> 2, wc = wid & 3;
    const int lr = lane & 15, lg = lane >> 4;
    const int swz = lr & 7;
    f32x4 acc[4][2] = {};
    const char* aBase = (const char*)sm.ab[0] + (wr * 64 + lr) * 512;
    const char* bBase = (const char*)sm.ab[1] + (wc * 32 + lr) * 512;
    #pragma unroll
    for (int ks = 0; ks < 8; ++ks) {
        bf16x8 a[4], bfr[2];
        #pragma unroll
        for (int mf = 0; mf < 4; ++mf)
            a[mf] = *(const bf16x8*)(aBase + mf * 16 * 512 + (((ks * 4 + lg) ^ swz) << 4));
        #pragma unroll
        for (int nf = 0; nf < 2; ++nf)
            bfr[nf] = *(const bf16x8*)(bBase + nf * 16 * 512 + (((ks * 4 + lg) ^ swz) << 4));
        #pragma unroll
        for (int mf = 0; mf < 4; ++mf)
            #pragma unroll
            for (int nf = 0; nf < 2; ++nf)
                acc[mf][nf] = __builtin_amdgcn_mfma_f32_16x16x32_bf16(a[mf], bfr[nf], acc[mf][nf], 0, 0, 0);
    }
    __syncthreads();

    float bocol[2];
    #pragma unroll
    for (int nf = 0; nf < 2; ++nf) bocol[nf] = bo[vb + wc * 32 + nf * 16 + lr];
    #pragma unroll
    for (int mf = 0; mf < 4; ++mf)
        #pragma unroll
        for (int nf = 0; nf < 2; ++nf)
            #pragma unroll
            for (int r = 0; r < 4; ++r) {
                int row = wr * 64 + mf * 16 + lg * 4 + r;
                int col = wc * 32 + nf * 16 + lr;
                sm.lg[row * 132 + col] = acc[mf][nf][r] + bocol[nf];
            }
    __syncthreads();

    {
        const int row = tid >> 2, q = tid & 3;
        const float* lp = &sm.lg[row * 132 + q * 32];
        float m = -1e30f;
        #pragma unroll
        for (int i = 0; i < 32; ++i) m = fmaxf(m, lp[i]);
        m = fmaxf(m, __shfl_xor(m, 1));
        m = fmaxf(m, __shfl_xor(m, 2));
        float s = 0.f;
        #pragma unroll
        for (int i = 0; i < 32; ++i) s += expf(lp[i] - m);
        s += __shfl_xor(s, 1);
        s += __shfl_xor(s, 2);
        if (q == 0) {
            const int gr = r0 + row;
            pm[(size_t)blockIdx.x * NROW + gr] = m;
            ps[(size_t)blockIdx.x * NROW + gr] = s;
            const int tt = gr >> 5, bb = gr & 31;
            const int tgt = x[bb * T + tt];
            if (tgt >= vb && tgt < vb + NC)
                tl[gr] = sm.lg[row * 132 + (tgt - vb)];
        }
    }
}

// ---------------- kernel 7: combine partials, reduce NLL ----------------------
__global__ __launch_bounds__(256) void lstm_lse(
        const float* __restrict__ pm, const float* __restrict__ ps,
        const float* __restrict__ tl, float* __restrict__ out) {
    const int row = blockIdx.x * 256 + threadIdx.x;
    float m = -1e30f, s = 0.f;
    for (int c = 0; c < NVB; ++c) {
        float mc = pm[(size_t)c * NROW + row];
        float sc = ps[(size_t)c * NROW + row];
        if (mc > m) { s = s * expf(m - mc) + sc; m = mc; }
        else        { s += sc * expf(mc - m); }
    }
    float nll = (m + logf(s)) - tl[row];
    __shared__ float red[256];
    red[threadIdx.x] = nll;
    __syncthreads();
    for (int off = 128; off > 0; off >>= 1) {
        if (threadIdx.x < off) red[threadIdx.x] += red[threadIdx.x + off];
        __syncthreads();
    }
    if (threadIdx.x == 0) atomicAdd(out, red[0]);
}

extern "C" void kernel_launch(void* const* d_in, const int* in_sizes, int n_in,
                              void* d_out, int out_size, void* d_ws, size_t ws_size,
                              hipStream_t stream) {
    const int*   x     = (const int*)d_in[0];
    const float* emb   = (const float*)d_in[1];
    const float* Wi    = (const float*)d_in[2];
    const float* Ui    = (const float*)d_in[3];
    const float* bi    = (const float*)d_in[4];
    const float* Wf    = (const float*)d_in[5];
    const float* Uf    = (const float*)d_in[6];
    const float* bf    = (const float*)d_in[7];
    const float* Wog   = (const float*)d_in[8];
    const float* Uog   = (const float*)d_in[9];
    const float* bog   = (const float*)d_in[10];
    const float* Wc    = (const float*)d_in[11];
    const float* Uc    = (const float*)d_in[12];
    const float* bc    = (const float*)d_in[13];
    const float* Wo    = (const float*)d_in[14];
    const float* bo    = (const float*)d_in[15];
    const int*   start = (const int*)d_in[16];
    float* ws  = (float*)d_ws;
    float* out = (float*)d_out;

    float*          xs  = ws + OFF_XS;
    unsigned short* xwT = (unsigned short*)(ws + OFF_XW);
    unsigned short* WoT = (unsigned short*)(ws + OFF_XW);   // aliases xwT (dead after recur)
    unsigned short* hbf = (unsigned short*)(ws + OFF_HB);
    float*          pm  = ws + OFF_PM;
    float*          psB = ws + OFF_PS;
    float*          tlB = ws + OFF_TL;
    unsigned short* UT  = (unsigned short*)(ws + OFF_UT);
    unsigned short* hcm = (unsigned short*)(ws + OFF_HC);
    unsigned int*   bar = (unsigned int*)(ws + OFF_BAR);

    lstm_embed <<<(T * B * E + 255) / 256, 256, 0, stream>>>(x, emb, start, xs, out, bar);
    lstm_xw    <<<T, 256, 0, stream>>>(xs, xwT, Wi, Wf, Wog, Wc, bi, bf, bog, bc);
    lstm_ut    <<<dim3(H / 64, H / 64, 4), 256, 0, stream>>>(Ui, Uf, Uog, Uc, UT);
    lstm_recur8<<<RB, 512, 0, stream>>>(xwT, UT, hcm, hbf, bar);
    lstm_wot   <<<dim3(V / 64, H / 64), 256, 0, stream>>>(Wo, WoT);
    lstm_logits_mfma<<<dim3(NVB, NROW / MR), 512, 0, stream>>>(hbf, WoT, bo, x, pm, psB, tlB);
    lstm_lse   <<<NROW / 256, 256, 0, stream>>>(pm, psB, tlB, out);
}

// Round 8
// 1403.101 us; speedup vs baseline: 1.8810x; 1.1268x over previous
//
#include <hip/hip_runtime.h>
#include <hip/hip_bf16.h>
#include <math.h>

#define V 32000
#define B 32
#define E 64
#define H 256
#define T 128
#define NROW (B*T)     // 4096 rows, row = t*B + b
#define NC 128         // vocab cols per block (logits)
#define NVB (V/NC)     // 250
#define MR 128         // rows per block (logits)

typedef __attribute__((ext_vector_type(8))) short bf16x8;
typedef __attribute__((ext_vector_type(4))) float f32x4;
typedef __attribute__((ext_vector_type(8))) unsigned short u16x8;

// ws layout (float offsets)
#define OFF_XS   0
#define OFF_XW   (OFF_XS + NROW*E)          // 262144  (xwT bf16 8MB; reused for WoT after recur)
#define OFF_HB   (OFF_XW + NROW*4*H)        // 4456448 (h bf16: NROW*H ushort = 2MB)
#define OFF_PM   (OFF_HB + NROW*H/2)        // 4980736
#define OFF_PS   (OFF_PM + NVB*NROW)        // 6004736
#define OFF_TL   (OFF_PS + NVB*NROW)        // 7028736 (+4096)
#define OFF_UT   (OFF_TL + NROW)            // 7032832 (UT bf16: 1024*256 ushort = 512KB)
#define OFF_CS   (OFF_UT + 4*H*H/2)         // 7163904 (c-state fp32: H*B = 8192) total ~28.7 MB

static __device__ __forceinline__ unsigned short f2bf(float f) {
    union { float f; unsigned int u; } x; x.f = f;
    unsigned int r = x.u + 0x7fffu + ((x.u >> 16) & 1u);   // RNE
    return (unsigned short)(r >> 16);
}
static __device__ __forceinline__ float bf2f(unsigned short u) {
    union { unsigned int u; float f; } x; x.u = ((unsigned int)u) << 16; return x.f;
}
static __device__ __forceinline__ float sigmoidf_(float x) { return 1.f / (1.f + __expf(-x)); }
static __device__ __forceinline__ float tanhf_(float x)    { return 2.f / (1.f + __expf(-2.f * x)) - 1.f; }

// ---------------- kernel 1: embedding gather (teacher forcing) ----------------
__global__ void lstm_embed(const int* __restrict__ x, const float* __restrict__ emb,
                           const int* __restrict__ start, float* __restrict__ xs,
                           float* __restrict__ out) {
    int idx = blockIdx.x * 256 + threadIdx.x;
    if (idx == 0) out[0] = 0.f;               // zero accumulator each launch (graph-replay safe)
    if (idx >= T * B * E) return;
    int t   = idx / (B * E);
    int rem = idx - t * (B * E);
    int b   = rem >> 6;
    int e   = rem & 63;
    int tok = (t == 0) ? start[0] : x[b * T + (t - 1)];
    xs[idx] = emb[tok * E + e];
}

// --- kernel 2: xwT[t][j][b][g] bf16 = (xs @ W_g + bias_g), block per t --------
__global__ __launch_bounds__(256) void lstm_xw(
        const float* __restrict__ xs, unsigned short* __restrict__ xwT,
        const float* __restrict__ Wi, const float* __restrict__ Wf,
        const float* __restrict__ Wog, const float* __restrict__ Wc,
        const float* __restrict__ bi, const float* __restrict__ bf,
        const float* __restrict__ bog, const float* __restrict__ bc) {
    __shared__ float xsl[32][65];
    const int t = blockIdx.x, tid = threadIdx.x;
    for (int i = tid; i < 32 * 64; i += 256) {
        int b = i >> 6, e = i & 63;
        xsl[b][e] = xs[(size_t)(t * 32 + b) * 64 + e];
    }
    __syncthreads();
    const int b = tid & 31, jg = tid >> 5;
    for (int jj = 0; jj < 32; ++jj) {
        const int j = jg * 32 + jj;
        float a0 = bi[j], a1 = bf[j], a2 = bog[j], a3 = bc[j];
        #pragma unroll 8
        for (int e = 0; e < E; ++e) {
            float xe = xsl[b][e];
            a0 += xe * Wi [e * H + j];
            a1 += xe * Wf [e * H + j];
            a2 += xe * Wog[e * H + j];
            a3 += xe * Wc [e * H + j];
        }
        ushort4 v;
        v.x = f2bf(a0); v.y = f2bf(a1); v.z = f2bf(a2); v.w = f2bf(a3);
        *(ushort4*)(xwT + ((size_t)(t * 256 + j) * 32 + b) * 4) = v;
    }
}

// ------ kernel 3: U_g[256][256] fp32 -> UT[(j*4+g)][k] bf16 (transposed) -------
__global__ __launch_bounds__(256) void lstm_ut(
        const float* __restrict__ Ui, const float* __restrict__ Uf,
        const float* __restrict__ Uog, const float* __restrict__ Uc,
        unsigned short* __restrict__ UT) {
    __shared__ unsigned short tle[64][65];
    const int g = blockIdx.z;
    const float* U = (g == 0) ? Ui : (g == 1) ? Uf : (g == 2) ? Uog : Uc;
    const int j0 = blockIdx.x * 64, k0 = blockIdx.y * 64;
    const int tid = threadIdx.x;
    for (int i = tid; i < 64 * 64; i += 256) {
        int kk = i >> 6, jj = i & 63;
        tle[kk][jj] = f2bf(U[(size_t)(k0 + kk) * H + j0 + jj]);
    }
    __syncthreads();
    for (int c = tid; c < 512; c += 256) {
        int jj = c >> 3, kc = c & 7;
        u16x8 v;
        #pragma unroll
        for (int e = 0; e < 8; ++e) v[e] = tle[kc * 8 + e][jj];
        *(u16x8*)(UT + ((size_t)(j0 + jj) * 4 + g) * H + k0 + kc * 8) = v;
    }
}

// ---- kernel 4: ONE recurrence step (t is a kernel arg; 128 chained dispatches)
// Sync between steps = kernel boundary (stream order) — architecturally
// coherent across XCDs, no fences/spins. Block blk owns j in [blk*32,+32);
// wave w owns gate-cols [blk*128+w*16,+16). Lane (lr,lg) reg r of acc{0,1} =
// gate r (i,f,o,cbar) of j=blk*32+w*4+lg for batch lr / 16+lr -> pointwise
// LSTM in-register. c-state in global cs[j*32+b] (32KB). Block->XCD mapping
// is deterministic per dispatch, so each block's 64KB UT slice stays L2-warm.
__global__ __launch_bounds__(512) void lstm_step(
        const unsigned short* __restrict__ xwT, const unsigned short* __restrict__ UT,
        unsigned short* __restrict__ hb, float* __restrict__ cs, int t) {
    __shared__ unsigned short h_pack[32][32];   // [batch][j_local]
    const int tid = threadIdx.x, blk = blockIdx.x;
    const int lane = tid & 63, w = tid >> 6;    // 8 waves
    const int lr = lane & 15, lg = lane >> 4;
    const int j = blk * 32 + w * 4 + lg;

    const unsigned short* xp = xwT + ((size_t)(t * 256 + j) * 32) * 4;
    ushort4 xw0 = *(const ushort4*)(xp + lr * 4);
    ushort4 xw1 = *(const ushort4*)(xp + (16 + lr) * 4);

    f32x4 acc0 = {}, acc1 = {};
    float c0 = 0.f, c1 = 0.f;
    if (t > 0) {
        c0 = cs[j * 32 + lr];
        c1 = cs[j * 32 + 16 + lr];
        const unsigned short* hsrc = hb + (size_t)(t - 1) * (B * H);
        const unsigned short* up   = UT + (size_t)(blk * 128 + w * 16 + lr) * H;
        #pragma unroll
        for (int kt = 0; kt < 8; ++kt) {
            bf16x8 Af = *(const bf16x8*)(up + kt * 32 + lg * 8);
            bf16x8 B0 = *(const bf16x8*)(hsrc + (size_t)lr * H + kt * 32 + lg * 8);
            bf16x8 B1 = *(const bf16x8*)(hsrc + (size_t)(16 + lr) * H + kt * 32 + lg * 8);
            acc0 = __builtin_amdgcn_mfma_f32_16x16x32_bf16(Af, B0, acc0, 0, 0, 0);
            acc1 = __builtin_amdgcn_mfma_f32_16x16x32_bf16(Af, B1, acc1, 0, 0, 0);
        }
    }
    // pointwise LSTM (gate quad in-lane: acc[r] = i,f,o,cbar)
    {
        float pi = bf2f(xw0.x) + acc0[0], pf = bf2f(xw0.y) + acc0[1];
        float po = bf2f(xw0.z) + acc0[2], pc = bf2f(xw0.w) + acc0[3];
        c0 = sigmoidf_(pf) * c0 + sigmoidf_(pi) * tanhf_(pc);
        cs[j * 32 + lr] = c0;
        h_pack[lr][w * 4 + lg] = f2bf(sigmoidf_(po) * tanhf_(c0));
        pi = bf2f(xw1.x) + acc1[0]; pf = bf2f(xw1.y) + acc1[1];
        po = bf2f(xw1.z) + acc1[2]; pc = bf2f(xw1.w) + acc1[3];
        c1 = sigmoidf_(pf) * c1 + sigmoidf_(pi) * tanhf_(pc);
        cs[j * 32 + 16 + lr] = c1;
        h_pack[16 + lr][w * 4 + lg] = f2bf(sigmoidf_(po) * tanhf_(c1));
    }
    __syncthreads();
    {   // pack-store this block's 2KB slice of h[t], coalesced dwords
        const int b = tid >> 4, dw = tid & 15;
        unsigned int dwv = *(const unsigned int*)&h_pack[b][dw * 2];
        *(unsigned int*)(hb + (size_t)(t * B + b) * H + blk * 32 + dw * 2) = dwv;
    }
}

// -------- kernel 5: Wo [K=256][V] fp32  ->  WoT [V][K=256] bf16 (transpose) ---
__global__ __launch_bounds__(256) void lstm_wot(const float* __restrict__ Wo,
                                                unsigned short* __restrict__ WoT) {
    __shared__ unsigned short tle[64][65];
    const int n0 = blockIdx.x * 64, k0 = blockIdx.y * 64;
    const int tid = threadIdx.x;
    for (int i = tid; i < 64 * 64; i += 256) {
        int kk = i >> 6, nn = i & 63;
        tle[kk][nn] = f2bf(Wo[(size_t)(k0 + kk) * V + n0 + nn]);
    }
    __syncthreads();
    for (int c = tid; c < 512; c += 256) {
        int nn = c >> 3, kc = c & 7;
        u16x8 v;
        #pragma unroll
        for (int e = 0; e < 8; ++e) v[e] = tle[kc * 8 + e][nn];
        *(u16x8*)(WoT + (size_t)(n0 + nn) * H + k0 + kc * 8) = v;
    }
}

// ------ kernel 6: bf16 MFMA logits GEMM + fused per-(row,vchunk) partials -----
__global__ __launch_bounds__(512) void lstm_logits_mfma(
        const unsigned short* __restrict__ hb, const unsigned short* __restrict__ WoT,
        const float* __restrict__ bo, const int* __restrict__ x,
        float* __restrict__ pm, float* __restrict__ ps, float* __restrict__ tl) {
    __shared__ union {
        unsigned short ab[2][MR * H];   // [0]=A tile 64KB, [1]=B tile 64KB
        float lg[MR * 132];             // logits buffer, used after MFMA
    } sm;
    const int tid = threadIdx.x;
    const int vb  = blockIdx.x * NC;
    const int r0  = blockIdx.y * MR;

    const uint4* srcA = (const uint4*)(hb  + (size_t)r0 * H);
    const uint4* srcB = (const uint4*)(WoT + (size_t)vb * H);
    for (int c = tid; c < MR * H / 8; c += 512) {
        int row = c >> 5, c16 = c & 31;
        uint4 va = srcA[c];
        *(uint4*)((char*)sm.ab[0] + row * 512 + ((c16 ^ (row & 7)) << 4)) = va;
        uint4 vbv = srcB[c];
        *(uint4*)((char*)sm.ab[1] + row * 512 + ((c16 ^ (row & 7)) << 4)) = vbv;
    }
    __syncthreads();

    const int lane = tid & 63, wid = tid >> 6;
    const int wr = wid >> 2, wc = wid & 3;
    const int lr = lane & 15, lg = lane >> 4;
    const int swz = lr & 7;
    f32x4 acc[4][2] = {};
    const char* aBase = (const char*)sm.ab[0] + (wr * 64 + lr) * 512;
    const char* bBase = (const char*)sm.ab[1] + (wc * 32 + lr) * 512;
    #pragma unroll
    for (int ks = 0; ks < 8; ++ks) {
        bf16x8 a[4], bfr[2];
        #pragma unroll
        for (int mf = 0; mf < 4; ++mf)
            a[mf] = *(const bf16x8*)(aBase + mf * 16 * 512 + (((ks * 4 + lg) ^ swz) << 4));
        #pragma unroll
        for (int nf = 0; nf < 2; ++nf)
            bfr[nf] = *(const bf16x8*)(bBase + nf * 16 * 512 + (((ks * 4 + lg) ^ swz) << 4));
        #pragma unroll
        for (int mf = 0; mf < 4; ++mf)
            #pragma unroll
            for (int nf = 0; nf < 2; ++nf)
                acc[mf][nf] = __builtin_amdgcn_mfma_f32_16x16x32_bf16(a[mf], bfr[nf], acc[mf][nf], 0, 0, 0);
    }
    __syncthreads();

    float bocol[2];
    #pragma unroll
    for (int nf = 0; nf < 2; ++nf) bocol[nf] = bo[vb + wc * 32 + nf * 16 + lr];
    #pragma unroll
    for (int mf = 0; mf < 4; ++mf)
        #pragma unroll
        for (int nf = 0; nf < 2; ++nf)
            #pragma unroll
            for (int r = 0; r < 4; ++r) {
                int row = wr * 64 + mf * 16 + lg * 4 + r;
                int col = wc * 32 + nf * 16 + lr;
                sm.lg[row * 132 + col] = acc[mf][nf][r] + bocol[nf];
            }
    __syncthreads();

    {
        const int row = tid >> 2, q = tid & 3;
        const float* lp = &sm.lg[row * 132 + q * 32];
        float m = -1e30f;
        #pragma unroll
        for (int i = 0; i < 32; ++i) m = fmaxf(m, lp[i]);
        m = fmaxf(m, __shfl_xor(m, 1));
        m = fmaxf(m, __shfl_xor(m, 2));
        float s = 0.f;
        #pragma unroll
        for (int i = 0; i < 32; ++i) s += expf(lp[i] - m);
        s += __shfl_xor(s, 1);
        s += __shfl_xor(s, 2);
        if (q == 0) {
            const int gr = r0 + row;
            pm[(size_t)blockIdx.x * NROW + gr] = m;
            ps[(size_t)blockIdx.x * NROW + gr] = s;
            const int tt = gr >> 5, bb = gr & 31;
            const int tgt = x[bb * T + tt];
            if (tgt >= vb && tgt < vb + NC)
                tl[gr] = sm.lg[row * 132 + (tgt - vb)];
        }
    }
}

// ---------------- kernel 7: combine partials, reduce NLL ----------------------
__global__ __launch_bounds__(256) void lstm_lse(
        const float* __restrict__ pm, const float* __restrict__ ps,
        const float* __restrict__ tl, float* __restrict__ out) {
    const int row = blockIdx.x * 256 + threadIdx.x;
    float m = -1e30f, s = 0.f;
    for (int c = 0; c < NVB; ++c) {
        float mc = pm[(size_t)c * NROW + row];
        float sc = ps[(size_t)c * NROW + row];
        if (mc > m) { s = s * expf(m - mc) + sc; m = mc; }
        else        { s += sc * expf(mc - m); }
    }
    float nll = (m + logf(s)) - tl[row];
    __shared__ float red[256];
    red[threadIdx.x] = nll;
    __syncthreads();
    for (int off = 128; off > 0; off >>= 1) {
        if (threadIdx.x < off) red[threadIdx.x] += red[threadIdx.x + off];
        __syncthreads();
    }
    if (threadIdx.x == 0) atomicAdd(out, red[0]);
}

extern "C" void kernel_launch(void* const* d_in, const int* in_sizes, int n_in,
                              void* d_out, int out_size, void* d_ws, size_t ws_size,
                              hipStream_t stream) {
    const int*   x     = (const int*)d_in[0];
    const float* emb   = (const float*)d_in[1];
    const float* Wi    = (const float*)d_in[2];
    const float* Ui    = (const float*)d_in[3];
    const float* bi    = (const float*)d_in[4];
    const float* Wf    = (const float*)d_in[5];
    const float* Uf    = (const float*)d_in[6];
    const float* bf    = (const float*)d_in[7];
    const float* Wog   = (const float*)d_in[8];
    const float* Uog   = (const float*)d_in[9];
    const float* bog   = (const float*)d_in[10];
    const float* Wc    = (const float*)d_in[11];
    const float* Uc    = (const float*)d_in[12];
    const float* bc    = (const float*)d_in[13];
    const float* Wo    = (const float*)d_in[14];
    const float* bo    = (const float*)d_in[15];
    const int*   start = (const int*)d_in[16];
    float* ws  = (float*)d_ws;
    float* out = (float*)d_out;

    float*          xs  = ws + OFF_XS;
    unsigned short* xwT = (unsigned short*)(ws + OFF_XW);
    unsigned short* WoT = (unsigned short*)(ws + OFF_XW);   // aliases xwT (dead after recur)
    unsigned short* hbf = (unsigned short*)(ws + OFF_HB);
    float*          pm  = ws + OFF_PM;
    float*          psB = ws + OFF_PS;
    float*          tlB = ws + OFF_TL;
    unsigned short* UT  = (unsigned short*)(ws + OFF_UT);
    float*          cst = ws + OFF_CS;

    lstm_embed <<<(T * B * E + 255) / 256, 256, 0, stream>>>(x, emb, start, xs, out);
    lstm_xw    <<<T, 256, 0, stream>>>(xs, xwT, Wi, Wf, Wog, Wc, bi, bf, bog, bc);
    lstm_ut    <<<dim3(H / 64, H / 64, 4), 256, 0, stream>>>(Ui, Uf, Uog, Uc, UT);
    for (int t = 0; t < T; ++t)
        lstm_step<<<8, 512, 0, stream>>>(xwT, UT, hbf, cst, t);
    lstm_wot   <<<dim3(V / 64, H / 64), 256, 0, stream>>>(Wo, WoT);
    lstm_logits_mfma<<<dim3(NVB, NROW / MR), 512, 0, stream>>>(hbf, WoT, bo, x, pm, psB, tlB);
    lstm_lse   <<<NROW / 256, 256, 0, stream>>>(pm, psB, tlB, out);
}

// Round 9
// 1089.203 us; speedup vs baseline: 2.4231x; 1.2882x over previous
//
#include <hip/hip_runtime.h>
#include <hip/hip_bf16.h>
#include <math.h>

#define V 32000
#define B 32
#define E 64
#define H 256
#define T 128
#define NROW (B*T)     // 4096 rows, row = t*B + b
#define NC 128         // vocab cols per block (logits)
#define NVB (V/NC)     // 250

typedef __attribute__((ext_vector_type(8))) short bf16x8;
typedef __attribute__((ext_vector_type(4))) float f32x4;
typedef __attribute__((ext_vector_type(8))) unsigned short u16x8;

// ws layout (float offsets)
#define OFF_XS   0                          // xs fp32 [T*B][E]              1MB
#define OFF_XW   (OFF_XS + NROW*E)          // xwq bf16 [t][b][j][4] 8MB; WoT bf16 16MB aliases after recur
#define OFF_HB   (OFF_XW + NROW*4*H)        // hb bf16 [t*B+b][k]            2MB
#define OFF_PS   (OFF_HB + NROW*H/2)        // ps fp32 [NVB][NROW]           4MB
#define OFF_TL   (OFF_PS + NVB*NROW)        // tl fp32 [NROW]
#define OFF_UQ   (OFF_TL + NROW)            // UQ bf16 [k2][j][2k*4g]        512KB
#define OFF_TGT  (OFF_UQ + 4*H*H/2)         // tgtrow int [NROW]             16KB

static __device__ __forceinline__ unsigned short f2bf(float f) {
    union { float f; unsigned int u; } x; x.f = f;
    unsigned int r = x.u + 0x7fffu + ((x.u >> 16) & 1u);   // RNE
    return (unsigned short)(r >> 16);
}
static __device__ __forceinline__ float bf2f(unsigned short u) {
    union { unsigned int u; float f; } x; x.u = ((unsigned int)u) << 16; return x.f;
}
static __device__ __forceinline__ float sigmoidf_(float x) { return 1.f / (1.f + __expf(-x)); }
static __device__ __forceinline__ float tanhf_(float x)    { return 2.f / (1.f + __expf(-2.f * x)) - 1.f; }

// ------- kernel 1: embedding gather + target-row table + out zero -------------
__global__ void lstm_embed(const int* __restrict__ x, const float* __restrict__ emb,
                           const int* __restrict__ start, float* __restrict__ xs,
                           float* __restrict__ out, int* __restrict__ tgtrow) {
    int idx = blockIdx.x * 256 + threadIdx.x;
    if (idx == 0) out[0] = 0.f;               // zero accumulator each launch (graph-replay safe)
    if (idx < NROW) tgtrow[idx] = x[(idx & 31) * T + (idx >> 5)];   // tgt of row gr=t*32+b
    if (idx >= T * B * E) return;
    int t   = idx / (B * E);
    int rem = idx - t * (B * E);
    int b   = rem >> 6;
    int e   = rem & 63;
    int tok = (t == 0) ? start[0] : x[b * T + (t - 1)];
    xs[idx] = emb[tok * E + e];
}

// --- kernel 2: xwq[t][b][j][g] bf16 = (xs @ W_g + bias_g), block per t --------
__global__ __launch_bounds__(256) void lstm_xw(
        const float* __restrict__ xs, unsigned short* __restrict__ xwq,
        const float* __restrict__ Wi, const float* __restrict__ Wf,
        const float* __restrict__ Wog, const float* __restrict__ Wc,
        const float* __restrict__ bi, const float* __restrict__ bf,
        const float* __restrict__ bog, const float* __restrict__ bc) {
    __shared__ float xsl[32][65];
    const int t = blockIdx.x, tid = threadIdx.x;
    for (int i = tid; i < 32 * 64; i += 256) {
        int b = i >> 6, e = i & 63;
        xsl[b][e] = xs[(size_t)(t * 32 + b) * 64 + e];
    }
    __syncthreads();
    const int b = tid & 31, jg = tid >> 5;
    for (int jj = 0; jj < 32; ++jj) {
        const int j = jg * 32 + jj;
        float a0 = bi[j], a1 = bf[j], a2 = bog[j], a3 = bc[j];
        #pragma unroll 8
        for (int e = 0; e < E; ++e) {
            float xe = xsl[b][e];
            a0 += xe * Wi [e * H + j];
            a1 += xe * Wf [e * H + j];
            a2 += xe * Wog[e * H + j];
            a3 += xe * Wc [e * H + j];
        }
        ushort4 v;
        v.x = f2bf(a0); v.y = f2bf(a1); v.z = f2bf(a2); v.w = f2bf(a3);
        *(ushort4*)(xwq + ((size_t)(t * 32 + b) * 256 + j) * 4) = v;
    }
}

// ---- kernel 3: U_g[k][j] fp32 -> UQ[k2][j][kk*4+g] bf16 (k-major, quad-packed)
__global__ __launch_bounds__(256) void lstm_uq(
        const float* __restrict__ Ui, const float* __restrict__ Uf,
        const float* __restrict__ Uog, const float* __restrict__ Uc,
        unsigned short* __restrict__ UQ) {
    int idx = blockIdx.x * 256 + threadIdx.x;   // 128 k2 x 256 j
    int k2 = idx >> 8, j = idx & 255;
    u16x8 v;
    #pragma unroll
    for (int kk = 0; kk < 2; ++kk) {
        int k = k2 * 2 + kk;
        v[kk * 4 + 0] = f2bf(Ui [(size_t)k * H + j]);
        v[kk * 4 + 1] = f2bf(Uf [(size_t)k * H + j]);
        v[kk * 4 + 2] = f2bf(Uog[(size_t)k * H + j]);
        v[kk * 4 + 3] = f2bf(Uc [(size_t)k * H + j]);
    }
    *(u16x8*)(UQ + (size_t)idx * 8) = v;
}

// ---- kernel 4: recurrence — 32 independent blocks, ONE dispatch, no sync -----
// Block b owns batch row b for all T steps. Thread j owns gate quad (i,f,o,cbar)
// of hidden unit j: 4 dot products over k, U streamed from L2 (k-major UQ,
// 16B/lane coalesced), h ping-pong in LDS (broadcast reads), c in a register.
// No inter-block communication anywhere -> no coherence cost, no deadlock risk.
__global__ __launch_bounds__(256) void lstm_recur_row(
        const unsigned short* __restrict__ xwq, const unsigned short* __restrict__ UQ,
        unsigned short* __restrict__ hb) {
    __shared__ unsigned short hl[2][256];
    const int b = blockIdx.x, j = threadIdx.x;
    float c;
    {   // t = 0: gates = xw only (h0 = c0 = 0)
        ushort4 xw = *(const ushort4*)(xwq + ((size_t)b * 256 + j) * 4);
        float pi = bf2f(xw.x), po = bf2f(xw.z), pc = bf2f(xw.w);
        c = sigmoidf_(pi) * tanhf_(pc);
        unsigned short h16 = f2bf(sigmoidf_(po) * tanhf_(c));
        hl[1][j] = h16;
        hb[(size_t)b * H + j] = h16;
    }
    __syncthreads();
    for (int t = 1; t < T; ++t) {
        const unsigned short* hr = hl[t & 1];
        ushort4 xw = *(const ushort4*)(xwq + ((size_t)(t * B + b) * 256 + j) * 4);
        float ai = bf2f(xw.x), af = bf2f(xw.y), ao = bf2f(xw.z), ac = bf2f(xw.w);
        const unsigned short* up = UQ + (size_t)j * 8;
        #pragma unroll 8
        for (int k2 = 0; k2 < 128; ++k2) {
            u16x8 uv = *(const u16x8*)(up + (size_t)k2 * 2048);
            unsigned int hp = *(const unsigned int*)&hr[k2 * 2];
            float h0 = bf2f((unsigned short)(hp & 0xffffu));
            float h1 = bf2f((unsigned short)(hp >> 16));
            ai += h0 * bf2f((unsigned short)uv[0]); af += h0 * bf2f((unsigned short)uv[1]);
            ao += h0 * bf2f((unsigned short)uv[2]); ac += h0 * bf2f((unsigned short)uv[3]);
            ai += h1 * bf2f((unsigned short)uv[4]); af += h1 * bf2f((unsigned short)uv[5]);
            ao += h1 * bf2f((unsigned short)uv[6]); ac += h1 * bf2f((unsigned short)uv[7]);
        }
        c = sigmoidf_(af) * c + sigmoidf_(ai) * tanhf_(ac);
        unsigned short h16 = f2bf(sigmoidf_(ao) * tanhf_(c));
        hl[(t + 1) & 1][j] = h16;
        hb[(size_t)(t * B + b) * H + j] = h16;
        __syncthreads();
    }
}

// -------- kernel 5: Wo [K=256][V] fp32  ->  WoT [V][K=256] bf16 (transpose) ---
__global__ __launch_bounds__(256) void lstm_wot(const float* __restrict__ Wo,
                                                unsigned short* __restrict__ WoT) {
    __shared__ unsigned short tle[64][65];
    const int n0 = blockIdx.x * 64, k0 = blockIdx.y * 64;
    const int tid = threadIdx.x;
    for (int i = tid; i < 64 * 64; i += 256) {
        int kk = i >> 6, nn = i & 63;
        tle[kk][nn] = f2bf(Wo[(size_t)(k0 + kk) * V + n0 + nn]);
    }
    __syncthreads();
    for (int c = tid; c < 512; c += 256) {
        int nn = c >> 3, kc = c & 7;
        u16x8 v;
        #pragma unroll
        for (int e = 0; e < 8; ++e) v[e] = tle[kc * 8 + e][nn];
        *(u16x8*)(WoT + (size_t)(n0 + nn) * H + k0 + kc * 8) = v;
    }
}

// ---- kernel 6: logits GEMM, B-tile in VGPRs, r0-loop, max-free fused softmax -
// One block per 128-col vocab chunk. WoT slice staged once (LDS->64 VGPR/lane),
// then 32 A-tiles of hb (L2-resident) stream through LDS. Softmax partial sums
// computed fully in-register (logits bounded -> exp without max subtraction),
// reduced over the 16 col-lanes by shfl_xor, combined across the 4 col-waves
// via a tiny padded LDS array. pm buffer eliminated.
__global__ __launch_bounds__(512, 2) void lstm_logits_mfma(
        const unsigned short* __restrict__ hb, const unsigned short* __restrict__ WoT,
        const float* __restrict__ bo, const int* __restrict__ tgtrow,
        float* __restrict__ ps, float* __restrict__ tl) {
    __shared__ char a_s[65536];          // A tile 64KB, XOR-swizzled 512B rows
    __shared__ char b_s[65536];          // B stage 64KB
    __shared__ float s_red[4][128];      // per-colwave row sums
    __shared__ int   tgt_l[128];
    const int tid = threadIdx.x, lane = tid & 63, wid = tid >> 6;
    const int wr = wid >> 2, wc = wid & 3;          // 2 row-halves x 4 col-quarters
    const int lr = lane & 15, lg = lane >> 4;
    const int swz = lr & 7;
    const int vb = blockIdx.x * NC;

    // ---- stage B slice (128 WoT rows), swizzled ----
    {
        const uint4* srcB = (const uint4*)(WoT + (size_t)vb * H);
        for (int c = tid; c < 4096; c += 512) {
            int row = c >> 5, c16 = c & 31;
            *(uint4*)(b_s + row * 512 + ((c16 ^ (row & 7)) << 4)) = srcB[c];
        }
    }
    __syncthreads();
    // ---- B fragments to registers: 2 nf x 8 ks = 64 VGPR ----
    bf16x8 Bf[2][8];
    {
        const char* bBase = b_s + (wc * 32 + lr) * 512;
        #pragma unroll
        for (int nf = 0; nf < 2; ++nf)
            #pragma unroll
            for (int ks = 0; ks < 8; ++ks)
                Bf[nf][ks] = *(const bf16x8*)(bBase + nf * 16 * 512 + (((ks * 4 + lg) ^ swz) << 4));
    }
    float bocol[2] = { bo[vb + wc * 32 + lr], bo[vb + wc * 32 + 16 + lr] };

    for (int rb = 0; rb < NROW / 128; ++rb) {
        // ---- stage A tile (128 hb rows), swizzled; stage targets ----
        {
            const uint4* srcA = (const uint4*)(hb + (size_t)rb * 128 * H);
            for (int c = tid; c < 4096; c += 512) {
                int row = c >> 5, c16 = c & 31;
                *(uint4*)(a_s + row * 512 + ((c16 ^ (row & 7)) << 4)) = srcA[c];
            }
            if (tid < 128) tgt_l[tid] = tgtrow[rb * 128 + tid];
        }
        __syncthreads();

        f32x4 acc[4][2] = {};
        const char* aBase = a_s + (wr * 64 + lr) * 512;
        #pragma unroll
        for (int ks = 0; ks < 8; ++ks) {
            bf16x8 a[4];
            #pragma unroll
            for (int mf = 0; mf < 4; ++mf)
                a[mf] = *(const bf16x8*)(aBase + mf * 16 * 512 + (((ks * 4 + lg) ^ swz) << 4));
            #pragma unroll
            for (int mf = 0; mf < 4; ++mf)
                #pragma unroll
                for (int nf = 0; nf < 2; ++nf)
                    acc[mf][nf] = __builtin_amdgcn_mfma_f32_16x16x32_bf16(a[mf], Bf[nf][ks], acc[mf][nf], 0, 0, 0);
        }

        // ---- fused softmax partials, in-register ----
        const int col0 = vb + wc * 32 + lr, col1 = col0 + 16;
        #pragma unroll
        for (int mf = 0; mf < 4; ++mf)
            #pragma unroll
            for (int r = 0; r < 4; ++r) {
                const int row_l = wr * 64 + mf * 16 + lg * 4 + r;
                float v0 = acc[mf][0][r] + bocol[0];
                float v1 = acc[mf][1][r] + bocol[1];
                const int tg = tgt_l[row_l];
                if (tg == col0) tl[rb * 128 + row_l] = v0;
                if (tg == col1) tl[rb * 128 + row_l] = v1;
                float e = __expf(v0) + __expf(v1);
                e += __shfl_xor(e, 1); e += __shfl_xor(e, 2);
                e += __shfl_xor(e, 4); e += __shfl_xor(e, 8);
                if (lr == 0) s_red[wc][row_l] = e;
            }
        __syncthreads();
        if (tid < 128)
            ps[(size_t)blockIdx.x * NROW + rb * 128 + tid] =
                s_red[0][tid] + s_red[1][tid] + s_red[2][tid] + s_red[3][tid];
        __syncthreads();
    }
}

// ---------------- kernel 7: combine chunk sums, reduce NLL --------------------
__global__ __launch_bounds__(256) void lstm_lse(
        const float* __restrict__ ps, const float* __restrict__ tl,
        float* __restrict__ out) {
    const int row = blockIdx.x * 256 + threadIdx.x;
    float s = 0.f;
    for (int c = 0; c < NVB; ++c) s += ps[(size_t)c * NROW + row];
    float nll = logf(s) - tl[row];
    __shared__ float red[256];
    red[threadIdx.x] = nll;
    __syncthreads();
    for (int off = 128; off > 0; off >>= 1) {
        if (threadIdx.x < off) red[threadIdx.x] += red[threadIdx.x + off];
        __syncthreads();
    }
    if (threadIdx.x == 0) atomicAdd(out, red[0]);
}

extern "C" void kernel_launch(void* const* d_in, const int* in_sizes, int n_in,
                              void* d_out, int out_size, void* d_ws, size_t ws_size,
                              hipStream_t stream) {
    const int*   x     = (const int*)d_in[0];
    const float* emb   = (const float*)d_in[1];
    const float* Wi    = (const float*)d_in[2];
    const float* Ui    = (const float*)d_in[3];
    const float* bi    = (const float*)d_in[4];
    const float* Wf    = (const float*)d_in[5];
    const float* Uf    = (const float*)d_in[6];
    const float* bf    = (const float*)d_in[7];
    const float* Wog   = (const float*)d_in[8];
    const float* Uog   = (const float*)d_in[9];
    const float* bog   = (const float*)d_in[10];
    const float* Wc    = (const float*)d_in[11];
    const float* Uc    = (const float*)d_in[12];
    const float* bc    = (const float*)d_in[13];
    const float* Wo    = (const float*)d_in[14];
    const float* bo    = (const float*)d_in[15];
    const int*   start = (const int*)d_in[16];
    float* ws  = (float*)d_ws;
    float* out = (float*)d_out;

    float*          xs   = ws + OFF_XS;
    unsigned short* xwq  = (unsigned short*)(ws + OFF_XW);
    unsigned short* WoT  = (unsigned short*)(ws + OFF_XW);   // aliases xwq (dead after recur)
    unsigned short* hbf  = (unsigned short*)(ws + OFF_HB);
    float*          psB  = ws + OFF_PS;
    float*          tlB  = ws + OFF_TL;
    unsigned short* UQ   = (unsigned short*)(ws + OFF_UQ);
    int*            tgtr = (int*)(ws + OFF_TGT);

    lstm_embed <<<(T * B * E + 255) / 256, 256, 0, stream>>>(x, emb, start, xs, out, tgtr);
    lstm_xw    <<<T, 256, 0, stream>>>(xs, xwq, Wi, Wf, Wog, Wc, bi, bf, bog, bc);
    lstm_uq    <<<(H / 2) * H / 256, 256, 0, stream>>>(Ui, Uf, Uog, Uc, UQ);
    lstm_recur_row<<<B, 256, 0, stream>>>(xwq, UQ, hbf);
    lstm_wot   <<<dim3(V / 64, H / 64), 256, 0, stream>>>(Wo, WoT);
    lstm_logits_mfma<<<NVB, 512, 0, stream>>>(hbf, WoT, bo, tgtr, psB, tlB);
    lstm_lse   <<<NROW / 256, 256, 0, stream>>>(psB, tlB, out);
}